// Round 5
// baseline (196.393 us; speedup 1.0000x reference)
//
#include <hip/hip_runtime.h>

// GQA layer, bf16 MFMA pipeline v4.
//   cvt5: x,wq,wk,wv,wo -> bf16 + bias concat (one launch);
//   QKV = x@[wq;wk;wv]^T+b (128x64 GEMM, Q pre-scaled 0.125*log2e for exp2
//   softmax); kvrepack -> Kp[8][2048][64], Vt[8][64][2048];
//   attn: swapped-QK^T 32x32 MFMA flash, in-register exp2 softmax,
//         intra-block split-K (8 waves = 4 heads x 2 key parities, LDS merge);
//   out = Ob@wo^T+bo.

#define S_LEN 2048
#define DM    2048
#define QKVW  3072   // Q|K|V row width

typedef float  f32x4  __attribute__((ext_vector_type(4)));
typedef float  f32x16 __attribute__((ext_vector_type(16)));
typedef __bf16 bf16x8 __attribute__((ext_vector_type(8)));
typedef unsigned short u16;
typedef unsigned int   u32;
typedef u16 u16x8 __attribute__((ext_vector_type(8)));
typedef u32 u32x4 __attribute__((ext_vector_type(4)));

__device__ __forceinline__ u16 f2b(float f) {
    __bf16 h = (__bf16)f;
    return __builtin_bit_cast(unsigned short, h);
}
__device__ __forceinline__ u32 pk2(float lo, float hi) {
    return (u32)f2b(lo) | ((u32)f2b(hi) << 16);
}

#define MFMA16(a, b, c) __builtin_amdgcn_mfma_f32_16x16x32_bf16((a), (b), (c), 0, 0, 0)
#define MFMA32(a, b, c) __builtin_amdgcn_mfma_f32_32x32x16_bf16((a), (b), (c), 0, 0, 0)

__device__ __forceinline__ void gld16(const void* g, void* l) {
    __builtin_amdgcn_global_load_lds(
        (const __attribute__((address_space(1))) void*)g,
        (__attribute__((address_space(3))) void*)l, 16, 0, 0);
}

// ---------------------------------------------------------------------------
__global__ __launch_bounds__(256) void cvt5(
    const float* __restrict__ x,  const float* __restrict__ wq,
    const float* __restrict__ wk, const float* __restrict__ wv,
    const float* __restrict__ wo,
    const float* __restrict__ bq, const float* __restrict__ bk,
    const float* __restrict__ bv,
    u16* __restrict__ xb, u16* __restrict__ wqkvb, u16* __restrict__ wob,
    float* __restrict__ bqkv)
{
    if (blockIdx.x == 7168) {
        for (int i = threadIdx.x; i < 3072; i += 256)
            bqkv[i] = (i < 2048) ? bq[i] : (i < 2560 ? bk[i - 2048] : bv[i - 2560]);
        return;
    }
    int i = blockIdx.x * 256 + threadIdx.x;
    const float* s; u16* d; int off;
    if      (i < 524288)  { s = x;  d = xb;    off = i; }
    else if (i < 1048576) { s = wq; d = wqkvb; off = i - 524288; }
    else if (i < 1179648) { s = wk; d = wqkvb + (size_t)2048 * 2048; off = i - 1048576; }
    else if (i < 1310720) { s = wv; d = wqkvb + (size_t)2560 * 2048; off = i - 1179648; }
    else                  { s = wo; d = wob;   off = i - 1310720; }
    const float4* s4 = (const float4*)s;
    float4 a = s4[2 * (size_t)off], b = s4[2 * (size_t)off + 1];
    u16x8 o;
    o[0] = f2b(a.x); o[1] = f2b(a.y); o[2] = f2b(a.z); o[3] = f2b(a.w);
    o[4] = f2b(b.x); o[5] = f2b(b.y); o[6] = f2b(b.z); o[7] = f2b(b.w);
    ((u16x8*)d)[(size_t)off] = o;
}

// ---------------------------------------------------------------------------
// NT GEMM, bf16 in / fp32 acc. 128x64 tile, BK=32, 4 waves, bijective XCD
// swizzle. QSCALE: cols<2048 scaled by 0.125*log2(e) (exp2-domain softmax).
// ---------------------------------------------------------------------------
template <bool OUT_BF16, bool QSCALE>
__global__ __launch_bounds__(256) void gemm_nt64(
    const u16* __restrict__ A, const u16* __restrict__ B,
    const float* __restrict__ bias, void* __restrict__ Cv,
    int N, int K, int nxb)
{
    __shared__ u16 As[128 * 32];
    __shared__ u16 Bs[64 * 32];
    const int nwg = gridDim.x;
    const int bid = blockIdx.x;
    const int wg  = (bid & 7) * (nwg >> 3) + (bid >> 3);
    const int bm  = (wg / nxb) * 128;
    const int bn  = (wg % nxb) * 64;

    const int tid  = threadIdx.x;
    const int lane = tid & 63;
    const int w    = tid >> 6;
    const int wr   = w >> 1, wc = w & 1;
    const int la = lane & 15, lg = lane >> 4;
    const int srow = lane >> 2;
    const int sseg = (lane & 3) * 8;

    f32x4 acc[4][2] = {};

    for (int k0 = 0; k0 < K; k0 += 32) {
        #pragma unroll
        for (int i = 0; i < 2; ++i) {
            const int c = w * 2 + i;
            gld16(A + (size_t)(bm + c * 16 + srow) * K + k0 + sseg, As + c * 512);
        }
        gld16(B + (size_t)(bn + w * 16 + srow) * K + k0 + sseg, Bs + w * 512);
        __syncthreads();
        bf16x8 af[4], bf[2];
        #pragma unroll
        for (int m = 0; m < 4; ++m)
            af[m] = *(const bf16x8*)(As + (wr * 64 + m * 16 + la) * 32 + lg * 8);
        #pragma unroll
        for (int n = 0; n < 2; ++n)
            bf[n] = *(const bf16x8*)(Bs + (wc * 32 + n * 16 + la) * 32 + lg * 8);
        #pragma unroll
        for (int m = 0; m < 4; ++m)
            #pragma unroll
            for (int n = 0; n < 2; ++n)
                acc[m][n] = MFMA16(af[m], bf[n], acc[m][n]);
        __syncthreads();
    }

    #pragma unroll
    for (int m = 0; m < 4; ++m) {
        #pragma unroll
        for (int n = 0; n < 2; ++n) {
            const int col = bn + wc * 32 + n * 16 + la;
            const float bb = bias[col];
            const float osc = (QSCALE && col < 2048) ? 0.180336881f : 1.0f;
            #pragma unroll
            for (int j = 0; j < 4; ++j) {
                const int row = bm + wr * 64 + m * 16 + lg * 4 + j;
                const float v = (acc[m][n][j] + bb) * osc;
                if (OUT_BF16) ((u16*)Cv)[(size_t)row * N + col] = f2b(v);
                else          ((float*)Cv)[(size_t)row * N + col] = v;
            }
        }
    }
}

// ---------------------------------------------------------------------------
__global__ __launch_bounds__(256) void kvrepack(const u16* __restrict__ QKVb,
                                                u16* __restrict__ Kp,
                                                u16* __restrict__ Vt) {
    const int h   = blockIdx.y;
    const int kt  = blockIdx.x;
    const int tid = threadIdx.x;
    __shared__ u16 T[64][72];
    #pragma unroll
    for (int p = 0; p < 2; ++p) {
        const int idx = p * 256 + tid;
        const int r   = idx >> 3;
        const int c8  = (idx & 7) * 8;
        *(u16x8*)&Kp[((size_t)h * S_LEN + kt * 64 + r) * 64 + c8] =
            *(const u16x8*)&QKVb[(size_t)(kt * 64 + r) * QKVW + 2048 + h * 64 + c8];
    }
    #pragma unroll
    for (int p = 0; p < 2; ++p) {
        const int r  = p * 32 + (tid >> 3);
        const int cs = (tid & 7) * 8;
        u16x8 v = *(const u16x8*)&QKVb[(size_t)(kt * 64 + r) * QKVW + 2560 + h * 64 + cs];
        #pragma unroll
        for (int j = 0; j < 8; ++j) T[r][cs + j] = v[j];
    }
    __syncthreads();
    #pragma unroll
    for (int p = 0; p < 2; ++p) {
        const int d  = p * 32 + (tid >> 3);
        const int ks = (tid & 7) * 8;
        u16x8 o;
        #pragma unroll
        for (int j = 0; j < 8; ++j) o[j] = T[ks + j][d];
        *(u16x8*)&Vt[((size_t)h * 64 + d) * S_LEN + kt * 64 + ks] = o;
    }
}

// ---------------------------------------------------------------------------
// Flash attention, swapped-QK^T 32x32 MFMA, exp2-domain in-register softmax,
// intra-block split-K. Block = (32-row q-tile, kv-head): 8 waves = 4 q-heads
// x 2 key-parities. Wave p handles chunks c ≡ p (mod 2). Upper waves (p=1)
// deposit unnormalized U, m, l in LDS; lower waves merge (LSE) and store.
// ---------------------------------------------------------------------------
__global__ __launch_bounds__(512, 4) void attn(
    const u16* __restrict__ Qb,   // QKVb [2048][3072], Q cols pre-scaled
    const u16* __restrict__ Kp,   // [8][2048][64]
    const u16* __restrict__ Vt,   // [8][64][2048]
    u16* __restrict__ Ob)         // [2048][2048] bf16
{
    const int lane = threadIdx.x & 63;
    const int w    = threadIdx.x >> 6;   // 0..7
    const int head = w & 3;              // q-head within group
    const int par  = w >> 2;             // key parity
    const int bid  = blockIdx.x;
    const int t    = 63 - (bid >> 3);    // longest blocks first
    const int h    = bid & 7;
    const int hq   = h * 4 + head;
    const int q0   = t * 32;
    const int lq   = lane & 31;
    const int hi   = lane >> 5;

    __shared__ float Uls[4][32][64];
    __shared__ float Mls[4][32];
    __shared__ float Lls[4][32];

    bf16x8 qf[4];
    #pragma unroll
    for (int ds = 0; ds < 4; ++ds)
        qf[ds] = *(const bf16x8*)&Qb[(size_t)(q0 + lq) * QKVW + hq * 64 + ds * 16 + hi * 8];

    f32x16 ot[2] = {};
    float m = -3e38f, lsum = 0.f;

    const u16* Kh = Kp + (size_t)h * S_LEN * 64;
    const u16* Vh = Vt + (size_t)h * 64 * S_LEN;

    const int nch = (q0 >> 6) + 1;
    for (int c = par; c < nch; c += 2) {
        const int k0 = c * 64;
        const bool diag = (k0 + 63 > q0);

        // ---- QK^T (swapped): S^T[key][q], exp2 domain
        f32x16 s[2];
        __builtin_amdgcn_s_setprio(1);
        #pragma unroll
        for (int kt = 0; kt < 2; ++kt) {
            f32x16 acc = {};
            #pragma unroll
            for (int ds = 0; ds < 4; ++ds) {
                bf16x8 kf = *(const bf16x8*)&Kh[
                    (size_t)(k0 + kt * 32 + lq) * 64 + ds * 16 + hi * 8];
                acc = MFMA32(kf, qf[ds], acc);
            }
            s[kt] = acc;
        }
        __builtin_amdgcn_s_setprio(0);

        if (diag) {
            #pragma unroll
            for (int kt = 0; kt < 2; ++kt)
                #pragma unroll
                for (int r = 0; r < 16; ++r) {
                    const int key = k0 + kt * 32 + (r & 3) + 8 * (r >> 2) + 4 * hi;
                    if (key > q0 + lq) s[kt][r] = -1e30f;
                }
        }

        // ---- chunk max: pairwise tree (depth 6)
        float a16[16];
        #pragma unroll
        for (int r = 0; r < 16; ++r) a16[r] = fmaxf(s[0][r], s[1][r]);
        #pragma unroll
        for (int r = 0; r < 8; ++r) a16[r] = fmaxf(a16[r], a16[r + 8]);
        #pragma unroll
        for (int r = 0; r < 4; ++r) a16[r] = fmaxf(a16[r], a16[r + 4]);
        float pm = fmaxf(fmaxf(a16[0], a16[1]), fmaxf(a16[2], a16[3]));
        pm = fmaxf(pm, __shfl_xor(pm, 32));

        // ---- defer-max rescale (exp2 domain, THR = 8*log2e)
        if (!__all(pm <= m + 11.5f)) {
            const float mn   = fmaxf(m, pm);
            const float corr = __builtin_exp2f(m - mn);
            m = mn;
            lsum *= corr;
            #pragma unroll
            for (int r = 0; r < 16; ++r) {
                const int row = (r & 3) + 8 * (r >> 2) + 4 * hi;
                const float cr = __shfl(corr, row);
                ot[0][r] *= cr;
                ot[1][r] *= cr;
            }
        }

        // ---- P = exp2(S - m), row sums
        float ps = 0.f;
        #pragma unroll
        for (int kt = 0; kt < 2; ++kt)
            #pragma unroll
            for (int r = 0; r < 16; ++r) {
                const float p = __builtin_exp2f(s[kt][r] - m);
                s[kt][r] = p;
                ps += p;
            }
        lsum += ps + __shfl_xor(ps, 32);

        // ---- pack P -> 4 PV A-frags
        bf16x8 pa[4];
        #pragma unroll
        for (int kb = 0; kb < 4; ++kb) {
            const int kt = kb >> 1;
            const int rb = (kb & 1) * 8;
            const u32 A = pk2(s[kt][rb + 0], s[kt][rb + 1]);
            const u32 B = pk2(s[kt][rb + 4], s[kt][rb + 5]);
            const u32 C = pk2(s[kt][rb + 2], s[kt][rb + 3]);
            const u32 D = pk2(s[kt][rb + 6], s[kt][rb + 7]);
            const u32 sA = __shfl_xor(A, 32), sB = __shfl_xor(B, 32);
            const u32 sC = __shfl_xor(C, 32), sD = __shfl_xor(D, 32);
            u32x4 t4;
            t4[0] = hi ? sB : A;
            t4[1] = hi ? sD : C;
            t4[2] = hi ? B : sA;
            t4[3] = hi ? D : sC;
            pa[kb] = __builtin_bit_cast(bf16x8, t4);
        }

        // ---- PV: U += P @ V
        __builtin_amdgcn_s_setprio(1);
        #pragma unroll
        for (int dt = 0; dt < 2; ++dt)
            #pragma unroll
            for (int kb = 0; kb < 4; ++kb) {
                bf16x8 vf = *(const bf16x8*)&Vh[
                    (size_t)(dt * 32 + lq) * S_LEN + k0 + kb * 16 + hi * 8];
                ot[dt] = MFMA32(pa[kb], vf, ot[dt]);
            }
        __builtin_amdgcn_s_setprio(0);
    }

    // ---- split-K merge via LDS
    if (par == 1) {
        #pragma unroll
        for (int r = 0; r < 16; ++r) {
            const int row = (r & 3) + 8 * (r >> 2) + 4 * hi;
            Uls[head][row][lq]      = ot[0][r];
            Uls[head][row][32 + lq] = ot[1][r];
        }
        if (lane < 32) { Mls[head][lane] = m; Lls[head][lane] = lsum; }
    }
    __syncthreads();
    if (par == 1) return;

    const float m1  = (lq < 32) ? Mls[head][lq] : 0.f;   // per-q stats (lane=q)
    const float l1  = (lq < 32) ? Lls[head][lq] : 0.f;
    const float M   = fmaxf(m, m1);
    const float a0  = __builtin_exp2f(m - M);
    const float a1  = __builtin_exp2f(m1 - M);
    const float inv = 1.f / (a0 * lsum + a1 * l1);

    #pragma unroll
    for (int r = 0; r < 16; ++r) {
        const int row = (r & 3) + 8 * (r >> 2) + 4 * hi;
        const float a0r = __shfl(a0, row);
        const float a1r = __shfl(a1, row);
        const float ivr = __shfl(inv, row);
        #pragma unroll
        for (int dt = 0; dt < 2; ++dt) {
            const float u1 = Uls[head][row][dt * 32 + lq];
            Ob[(size_t)(q0 + row) * DM + hq * 64 + dt * 32 + lq] =
                f2b((a0r * ot[dt][r] + a1r * u1) * ivr);
        }
    }
}

// ---------------------------------------------------------------------------
extern "C" void kernel_launch(void* const* d_in, const int* in_sizes, int n_in,
                              void* d_out, int out_size, void* d_ws, size_t ws_size,
                              hipStream_t stream)
{
    const float* x  = (const float*)d_in[0];
    const float* wq = (const float*)d_in[1];
    const float* bq = (const float*)d_in[2];
    const float* wk = (const float*)d_in[3];
    const float* bk = (const float*)d_in[4];
    const float* wv = (const float*)d_in[5];
    const float* bv = (const float*)d_in[6];
    const float* wo = (const float*)d_in[7];
    const float* bo = (const float*)d_in[8];
    float* out = (float*)d_out;

    char* ws = (char*)d_ws;
    u16* xb     = (u16*)(ws);                  // 8 MB; dead after QKV GEMM
    u16* wqkvb  = (u16*)(ws + (8u  << 20));    // 12 MB; dead after QKV GEMM
    u16* wob    = (u16*)(ws + (20u << 20));    // 8 MB
    u16* QKVb   = (u16*)(ws + (28u << 20));    // 12 MB
    float* bqkv = (float*)(ws + (40u << 20));  // 12 KB
    u16* Ob = xb;                              // 8 MB (aliases dead xb)
    u16* Kp = wqkvb;                           // 2 MB (aliases dead wqkvb)
    u16* Vt = wqkvb + (size_t)2 * 1024 * 1024 / 2;  // 2 MB

    cvt5<<<7169, 256, 0, stream>>>(x, wq, wk, wv, wo, bq, bk, bv,
                                   xb, wqkvb, wob, bqkv);
    gemm_nt64<true, true><<<768, 256, 0, stream>>>(
        xb, wqkvb, bqkv, QKVb, QKVW, 2048, QKVW / 64);
    kvrepack<<<dim3(32, 8), 256, 0, stream>>>(QKVb, Kp, Vt);
    attn<<<512, 512, 0, stream>>>(QKVb, Kp, Vt, Ob);
    gemm_nt64<false, false><<<512, 256, 0, stream>>>(
        Ob, wob, bo, out, DM, 2048, DM / 64);
}

// Round 7
// 184.057 us; speedup vs baseline: 1.0670x; 1.0670x over previous
//
#include <hip/hip_runtime.h>

// GQA layer, bf16 MFMA pipeline v5.1 (v5 + LDS double-buffer offset fix).
//   cvt5: x,wq,wk,wv,wo -> bf16 + bias concat;
//   QKV = x@[wq;wk;wv]^T+b (128x64 GEMM, Q pre-scaled 0.125*log2e);
//   kvrepack -> Kp[8][2048][64], Vt[8][64][2048];
//   attn: 8-wave blocks (4 heads x 2 q-subtiles) share LDS-staged K/V chunks
//         (double-buffered global_load_lds, XOR-swizzled via pre-swizzled src),
//         swapped-QK^T 32x32 MFMA, in-register exp2 softmax;
//   out = Ob@wo^T+bo.

#define S_LEN 2048
#define DM    2048
#define QKVW  3072   // Q|K|V row width

typedef float  f32x4  __attribute__((ext_vector_type(4)));
typedef float  f32x16 __attribute__((ext_vector_type(16)));
typedef __bf16 bf16x8 __attribute__((ext_vector_type(8)));
typedef unsigned short u16;
typedef unsigned int   u32;
typedef u16 u16x8 __attribute__((ext_vector_type(8)));
typedef u32 u32x4 __attribute__((ext_vector_type(4)));

__device__ __forceinline__ u16 f2b(float f) {
    __bf16 h = (__bf16)f;
    return __builtin_bit_cast(unsigned short, h);
}
__device__ __forceinline__ u32 pk2(float lo, float hi) {
    return (u32)f2b(lo) | ((u32)f2b(hi) << 16);
}

#define MFMA16(a, b, c) __builtin_amdgcn_mfma_f32_16x16x32_bf16((a), (b), (c), 0, 0, 0)
#define MFMA32(a, b, c) __builtin_amdgcn_mfma_f32_32x32x16_bf16((a), (b), (c), 0, 0, 0)

__device__ __forceinline__ void gld16(const void* g, void* l) {
    __builtin_amdgcn_global_load_lds(
        (const __attribute__((address_space(1))) void*)g,
        (__attribute__((address_space(3))) void*)l, 16, 0, 0);
}

// ---------------------------------------------------------------------------
__global__ __launch_bounds__(256) void cvt5(
    const float* __restrict__ x,  const float* __restrict__ wq,
    const float* __restrict__ wk, const float* __restrict__ wv,
    const float* __restrict__ wo,
    const float* __restrict__ bq, const float* __restrict__ bk,
    const float* __restrict__ bv,
    u16* __restrict__ xb, u16* __restrict__ wqkvb, u16* __restrict__ wob,
    float* __restrict__ bqkv)
{
    if (blockIdx.x == 7168) {
        for (int i = threadIdx.x; i < 3072; i += 256)
            bqkv[i] = (i < 2048) ? bq[i] : (i < 2560 ? bk[i - 2048] : bv[i - 2560]);
        return;
    }
    int i = blockIdx.x * 256 + threadIdx.x;
    const float* s; u16* d; int off;
    if      (i < 524288)  { s = x;  d = xb;    off = i; }
    else if (i < 1048576) { s = wq; d = wqkvb; off = i - 524288; }
    else if (i < 1179648) { s = wk; d = wqkvb + (size_t)2048 * 2048; off = i - 1048576; }
    else if (i < 1310720) { s = wv; d = wqkvb + (size_t)2560 * 2048; off = i - 1179648; }
    else                  { s = wo; d = wob;   off = i - 1310720; }
    const float4* s4 = (const float4*)s;
    float4 a = s4[2 * (size_t)off], b = s4[2 * (size_t)off + 1];
    u16x8 o;
    o[0] = f2b(a.x); o[1] = f2b(a.y); o[2] = f2b(a.z); o[3] = f2b(a.w);
    o[4] = f2b(b.x); o[5] = f2b(b.y); o[6] = f2b(b.z); o[7] = f2b(b.w);
    ((u16x8*)d)[(size_t)off] = o;
}

// ---------------------------------------------------------------------------
// NT GEMM, bf16 in / fp32 acc. 128x64 tile, BK=32, 4 waves, bijective XCD
// swizzle. QSCALE: cols<2048 scaled by 0.125*log2(e) (exp2-domain softmax).
// ---------------------------------------------------------------------------
template <bool OUT_BF16, bool QSCALE>
__global__ __launch_bounds__(256) void gemm_nt64(
    const u16* __restrict__ A, const u16* __restrict__ B,
    const float* __restrict__ bias, void* __restrict__ Cv,
    int N, int K, int nxb)
{
    __shared__ u16 As[128 * 32];
    __shared__ u16 Bs[64 * 32];
    const int nwg = gridDim.x;
    const int bid = blockIdx.x;
    const int wg  = (bid & 7) * (nwg >> 3) + (bid >> 3);
    const int bm  = (wg / nxb) * 128;
    const int bn  = (wg % nxb) * 64;

    const int tid  = threadIdx.x;
    const int lane = tid & 63;
    const int w    = tid >> 6;
    const int wr   = w >> 1, wc = w & 1;
    const int la = lane & 15, lg = lane >> 4;
    const int srow = lane >> 2;
    const int sseg = (lane & 3) * 8;

    f32x4 acc[4][2] = {};

    for (int k0 = 0; k0 < K; k0 += 32) {
        #pragma unroll
        for (int i = 0; i < 2; ++i) {
            const int c = w * 2 + i;
            gld16(A + (size_t)(bm + c * 16 + srow) * K + k0 + sseg, As + c * 512);
        }
        gld16(B + (size_t)(bn + w * 16 + srow) * K + k0 + sseg, Bs + w * 512);
        __syncthreads();
        bf16x8 af[4], bf[2];
        #pragma unroll
        for (int m = 0; m < 4; ++m)
            af[m] = *(const bf16x8*)(As + (wr * 64 + m * 16 + la) * 32 + lg * 8);
        #pragma unroll
        for (int n = 0; n < 2; ++n)
            bf[n] = *(const bf16x8*)(Bs + (wc * 32 + n * 16 + la) * 32 + lg * 8);
        #pragma unroll
        for (int m = 0; m < 4; ++m)
            #pragma unroll
            for (int n = 0; n < 2; ++n)
                acc[m][n] = MFMA16(af[m], bf[n], acc[m][n]);
        __syncthreads();
    }

    #pragma unroll
    for (int m = 0; m < 4; ++m) {
        #pragma unroll
        for (int n = 0; n < 2; ++n) {
            const int col = bn + wc * 32 + n * 16 + la;
            const float bb = bias[col];
            const float osc = (QSCALE && col < 2048) ? 0.180336881f : 1.0f;
            #pragma unroll
            for (int j = 0; j < 4; ++j) {
                const int row = bm + wr * 64 + m * 16 + lg * 4 + j;
                const float v = (acc[m][n][j] + bb) * osc;
                if (OUT_BF16) ((u16*)Cv)[(size_t)row * N + col] = f2b(v);
                else          ((float*)Cv)[(size_t)row * N + col] = v;
            }
        }
    }
}

// ---------------------------------------------------------------------------
__global__ __launch_bounds__(256) void kvrepack(const u16* __restrict__ QKVb,
                                                u16* __restrict__ Kp,
                                                u16* __restrict__ Vt) {
    const int h   = blockIdx.y;
    const int kt  = blockIdx.x;
    const int tid = threadIdx.x;
    __shared__ u16 T[64][72];
    #pragma unroll
    for (int p = 0; p < 2; ++p) {
        const int idx = p * 256 + tid;
        const int r   = idx >> 3;
        const int c8  = (idx & 7) * 8;
        *(u16x8*)&Kp[((size_t)h * S_LEN + kt * 64 + r) * 64 + c8] =
            *(const u16x8*)&QKVb[(size_t)(kt * 64 + r) * QKVW + 2048 + h * 64 + c8];
    }
    #pragma unroll
    for (int p = 0; p < 2; ++p) {
        const int r  = p * 32 + (tid >> 3);
        const int cs = (tid & 7) * 8;
        u16x8 v = *(const u16x8*)&QKVb[(size_t)(kt * 64 + r) * QKVW + 2560 + h * 64 + cs];
        #pragma unroll
        for (int j = 0; j < 8; ++j) T[r][cs + j] = v[j];
    }
    __syncthreads();
    #pragma unroll
    for (int p = 0; p < 2; ++p) {
        const int d  = p * 32 + (tid >> 3);
        const int ks = (tid & 7) * 8;
        u16x8 o;
        #pragma unroll
        for (int j = 0; j < 8; ++j) o[j] = T[ks + j][d];
        *(u16x8*)&Vt[((size_t)h * 64 + d) * S_LEN + kt * 64 + ks] = o;
    }
}

// ---------------------------------------------------------------------------
// Flash attention v5.1. Block = (64-row q-band, kv-head): 8 waves = 4 q-heads
// x 2 q-subtiles (32 rows each). Per 64-key chunk: K[64][64] and Vt[64][64]
// staged ONCE into LDS (global_load_lds, double-buffered, XOR-swizzled via
// pre-swizzled source) and shared by all 8 waves -> 8x less cache traffic.
// Each LDS buffer is 8192 B (64 rows x 128 B); buffer stride BUFB = 8192.
// ---------------------------------------------------------------------------
#define BUFB 8192   // bytes per K (or V) chunk buffer: 64 * 64 * 2

__global__ __launch_bounds__(512, 2) void attn(
    const u16* __restrict__ Qb,   // QKVb [2048][3072], Q cols pre-scaled
    const u16* __restrict__ Kp,   // [8][2048][64]
    const u16* __restrict__ Vt,   // [8][64][2048]
    u16* __restrict__ Ob)         // [2048][2048] bf16
{
    const int tid  = threadIdx.x;
    const int lane = tid & 63;
    const int w    = tid >> 6;           // 0..7
    const int head = w & 3;
    const int qsub = w >> 2;
    const int bid  = blockIdx.x;
    const int band = 31 - (bid >> 3);    // longest blocks first
    const int h    = bid & 7;            // XCD-aligned kv head
    const int hq   = h * 4 + head;
    const int q0   = band * 64 + qsub * 32;   // wave's 32 q rows
    const int lq   = lane & 31;
    const int hi   = lane >> 5;

    __shared__ u16 Klds[2][64 * 64];
    __shared__ u16 Vlds[2][64 * 64];

    bf16x8 qf[4];
    #pragma unroll
    for (int ds = 0; ds < 4; ++ds)
        qf[ds] = *(const bf16x8*)&Qb[(size_t)(q0 + lq) * QKVW + hq * 64 + ds * 16 + hi * 8];

    f32x16 ot[2] = {};
    float m = -3e38f, lsum = 0.f;

    const char* Khb = (const char*)(Kp + (size_t)h * S_LEN * 64);   // 128 B/key
    const char* Vhb = (const char*)(Vt + (size_t)h * 64 * S_LEN);   // 4096 B/d-row

    // staging geometry: thread stages one 16B K piece + one 16B V piece.
    const int srow = tid >> 3;                                  // 0..63
    const int scolb = ((tid & 7) << 4) ^ ((srow & 7) << 4);     // pre-swizzled
    char* const kdst = (char*)&Klds[0][0] + w * 1024;           // +BUFB for buf1
    char* const vdst = (char*)&Vlds[0][0] + w * 1024;

    const int nch = band + 1;

    // prologue: stage chunk 0 into buf 0
    gld16(Khb + ((size_t)srow << 7) + scolb, kdst);
    gld16(Vhb + ((size_t)srow << 12) + scolb, vdst);
    __syncthreads();

    int cur = 0;
    for (int c = 0; c < nch; ++c) {
        const int k0 = c * 64;

        // stage next chunk into the other buffer (overlaps with compute)
        if (c + 1 < nch) {
            const int nb = (cur ^ 1) * BUFB;
            gld16(Khb + ((size_t)(k0 + 64 + srow) << 7) + scolb, kdst + nb);
            gld16(Vhb + ((size_t)srow << 12) + ((k0 + 64) << 1) + scolb, vdst + nb);
        }

        const bool diag = (k0 + 63 > q0);
        const char* Kb = (const char*)&Klds[0][0] + cur * BUFB;
        const char* Vb = (const char*)&Vlds[0][0] + cur * BUFB;

        // ---- QK^T (swapped): S^T[key][q], exp2 domain
        f32x16 s[2];
        __builtin_amdgcn_s_setprio(1);
        #pragma unroll
        for (int kt = 0; kt < 2; ++kt) {
            f32x16 acc = {};
            #pragma unroll
            for (int ds = 0; ds < 4; ++ds) {
                const int key = kt * 32 + lq;
                const int byteK = (key << 7) + (((ds * 32 + hi * 16)) ^ ((key & 7) << 4));
                bf16x8 kf = *(const bf16x8*)(Kb + byteK);
                acc = MFMA32(kf, qf[ds], acc);
            }
            s[kt] = acc;
        }
        __builtin_amdgcn_s_setprio(0);

        if (diag) {
            #pragma unroll
            for (int kt = 0; kt < 2; ++kt)
                #pragma unroll
                for (int r = 0; r < 16; ++r) {
                    const int key = k0 + kt * 32 + (r & 3) + 8 * (r >> 2) + 4 * hi;
                    if (key > q0 + lq) s[kt][r] = -1e30f;
                }
        }

        // ---- chunk max: pairwise tree
        float a16[16];
        #pragma unroll
        for (int r = 0; r < 16; ++r) a16[r] = fmaxf(s[0][r], s[1][r]);
        #pragma unroll
        for (int r = 0; r < 8; ++r) a16[r] = fmaxf(a16[r], a16[r + 8]);
        #pragma unroll
        for (int r = 0; r < 4; ++r) a16[r] = fmaxf(a16[r], a16[r + 4]);
        float pm = fmaxf(fmaxf(a16[0], a16[1]), fmaxf(a16[2], a16[3]));
        pm = fmaxf(pm, __shfl_xor(pm, 32));

        // ---- defer-max rescale (exp2 domain, THR = 8*log2e)
        if (!__all(pm <= m + 11.5f)) {
            const float mn   = fmaxf(m, pm);
            const float corr = __builtin_exp2f(m - mn);
            m = mn;
            lsum *= corr;
            #pragma unroll
            for (int r = 0; r < 16; ++r) {
                const int row = (r & 3) + 8 * (r >> 2) + 4 * hi;
                const float cr = __shfl(corr, row);
                ot[0][r] *= cr;
                ot[1][r] *= cr;
            }
        }

        // ---- P = exp2(S - m), row sums
        float ps = 0.f;
        #pragma unroll
        for (int kt = 0; kt < 2; ++kt)
            #pragma unroll
            for (int r = 0; r < 16; ++r) {
                const float p = __builtin_exp2f(s[kt][r] - m);
                s[kt][r] = p;
                ps += p;
            }
        lsum += ps + __shfl_xor(ps, 32);

        // ---- pack P -> 4 PV A-frags
        bf16x8 pa[4];
        #pragma unroll
        for (int kb = 0; kb < 4; ++kb) {
            const int kt = kb >> 1;
            const int rb = (kb & 1) * 8;
            const u32 A = pk2(s[kt][rb + 0], s[kt][rb + 1]);
            const u32 B = pk2(s[kt][rb + 4], s[kt][rb + 5]);
            const u32 C = pk2(s[kt][rb + 2], s[kt][rb + 3]);
            const u32 D = pk2(s[kt][rb + 6], s[kt][rb + 7]);
            const u32 sA = __shfl_xor(A, 32), sB = __shfl_xor(B, 32);
            const u32 sC = __shfl_xor(C, 32), sD = __shfl_xor(D, 32);
            u32x4 t4;
            t4[0] = hi ? sB : A;
            t4[1] = hi ? sD : C;
            t4[2] = hi ? B : sA;
            t4[3] = hi ? D : sC;
            pa[kb] = __builtin_bit_cast(bf16x8, t4);
        }

        // ---- PV: O += P @ V
        __builtin_amdgcn_s_setprio(1);
        #pragma unroll
        for (int dt = 0; dt < 2; ++dt)
            #pragma unroll
            for (int kb = 0; kb < 4; ++kb) {
                const int d = dt * 32 + lq;
                const int byteV = (d << 7) + ((kb * 32 + hi * 16) ^ ((d & 7) << 4));
                bf16x8 vf = *(const bf16x8*)(Vb + byteV);
                ot[dt] = MFMA32(pa[kb], vf, ot[dt]);
            }
        __builtin_amdgcn_s_setprio(0);

        // drain stage loads + handoff (syncthreads emits full waitcnt drain)
        __syncthreads();
        cur ^= 1;
    }

    const float linv = 1.f / lsum;
    #pragma unroll
    for (int r = 0; r < 16; ++r) {
        const int row = (r & 3) + 8 * (r >> 2) + 4 * hi;
        const float lr = __shfl(linv, row);
        #pragma unroll
        for (int dt = 0; dt < 2; ++dt)
            Ob[(size_t)(q0 + row) * DM + hq * 64 + dt * 32 + lq] =
                f2b(ot[dt][r] * lr);
    }
}

// ---------------------------------------------------------------------------
extern "C" void kernel_launch(void* const* d_in, const int* in_sizes, int n_in,
                              void* d_out, int out_size, void* d_ws, size_t ws_size,
                              hipStream_t stream)
{
    const float* x  = (const float*)d_in[0];
    const float* wq = (const float*)d_in[1];
    const float* bq = (const float*)d_in[2];
    const float* wk = (const float*)d_in[3];
    const float* bk = (const float*)d_in[4];
    const float* wv = (const float*)d_in[5];
    const float* bv = (const float*)d_in[6];
    const float* wo = (const float*)d_in[7];
    const float* bo = (const float*)d_in[8];
    float* out = (float*)d_out;

    char* ws = (char*)d_ws;
    u16* xb     = (u16*)(ws);                  // 8 MB; dead after QKV GEMM
    u16* wqkvb  = (u16*)(ws + (8u  << 20));    // 12 MB; dead after QKV GEMM
    u16* wob    = (u16*)(ws + (20u << 20));    // 8 MB
    u16* QKVb   = (u16*)(ws + (28u << 20));    // 12 MB
    float* bqkv = (float*)(ws + (40u << 20));  // 12 KB
    u16* Ob = xb;                              // 8 MB (aliases dead xb)
    u16* Kp = wqkvb;                           // 2 MB (aliases dead wqkvb)
    u16* Vt = wqkvb + (size_t)2 * 1024 * 1024 / 2;  // 2 MB

    cvt5<<<7169, 256, 0, stream>>>(x, wq, wk, wv, wo, bq, bk, bv,
                                   xb, wqkvb, wob, bqkv);
    gemm_nt64<true, true><<<768, 256, 0, stream>>>(
        xb, wqkvb, bqkv, QKVb, QKVW, 2048, QKVW / 64);
    kvrepack<<<dim3(32, 8), 256, 0, stream>>>(QKVb, Kp, Vt);
    attn<<<256, 512, 0, stream>>>(QKVb, Kp, Vt, Ob);
    gemm_nt64<false, false><<<512, 256, 0, stream>>>(
        Ob, wob, bo, out, DM, 2048, DM / 64);
}

// Round 9
// 164.662 us; speedup vs baseline: 1.1927x; 1.1178x over previous
//
#include <hip/hip_runtime.h>

// GQA layer, bf16 MFMA pipeline v6.1 (v6 structure, v5.1 shuffle math).
//   cvt5: x,w* -> bf16 + bias concat; QKV GEMM (Q pre-scaled 0.125*log2e);
//   kvrepack -> Kp[8][2048][64], Vt[8][64][2048];
//   attn: 4-wave blocks (4 q-heads) x 32-row bands, 512 balanced blocks
//         (complementary pairs co-resident), LDS-staged K/V chunks (dbuf
//         gld16, XOR-swizzled src), swapped-QK^T 32x32 MFMA, in-register
//         exp2 softmax with __shfl_xor cross-half exchanges;
//   out = Ob@wo^T+bo.

#define S_LEN 2048
#define DM    2048
#define QKVW  3072   // Q|K|V row width

typedef float  f32x4  __attribute__((ext_vector_type(4)));
typedef float  f32x16 __attribute__((ext_vector_type(16)));
typedef __bf16 bf16x8 __attribute__((ext_vector_type(8)));
typedef unsigned short u16;
typedef unsigned int   u32;
typedef u16 u16x8 __attribute__((ext_vector_type(8)));
typedef u32 u32x4 __attribute__((ext_vector_type(4)));

__device__ __forceinline__ u16 f2b(float f) {
    __bf16 h = (__bf16)f;
    return __builtin_bit_cast(unsigned short, h);
}
__device__ __forceinline__ u32 pk2(float lo, float hi) {
    return (u32)f2b(lo) | ((u32)f2b(hi) << 16);
}

#define MFMA16(a, b, c) __builtin_amdgcn_mfma_f32_16x16x32_bf16((a), (b), (c), 0, 0, 0)
#define MFMA32(a, b, c) __builtin_amdgcn_mfma_f32_32x32x16_bf16((a), (b), (c), 0, 0, 0)

__device__ __forceinline__ void gld16(const void* g, void* l) {
    __builtin_amdgcn_global_load_lds(
        (const __attribute__((address_space(1))) void*)g,
        (__attribute__((address_space(3))) void*)l, 16, 0, 0);
}

// ---------------------------------------------------------------------------
__global__ __launch_bounds__(256) void cvt5(
    const float* __restrict__ x,  const float* __restrict__ wq,
    const float* __restrict__ wk, const float* __restrict__ wv,
    const float* __restrict__ wo,
    const float* __restrict__ bq, const float* __restrict__ bk,
    const float* __restrict__ bv,
    u16* __restrict__ xb, u16* __restrict__ wqkvb, u16* __restrict__ wob,
    float* __restrict__ bqkv)
{
    if (blockIdx.x == 7168) {
        for (int i = threadIdx.x; i < 3072; i += 256)
            bqkv[i] = (i < 2048) ? bq[i] : (i < 2560 ? bk[i - 2048] : bv[i - 2560]);
        return;
    }
    int i = blockIdx.x * 256 + threadIdx.x;
    const float* s; u16* d; int off;
    if      (i < 524288)  { s = x;  d = xb;    off = i; }
    else if (i < 1048576) { s = wq; d = wqkvb; off = i - 524288; }
    else if (i < 1179648) { s = wk; d = wqkvb + (size_t)2048 * 2048; off = i - 1048576; }
    else if (i < 1310720) { s = wv; d = wqkvb + (size_t)2560 * 2048; off = i - 1179648; }
    else                  { s = wo; d = wob;   off = i - 1310720; }
    const float4* s4 = (const float4*)s;
    float4 a = s4[2 * (size_t)off], b = s4[2 * (size_t)off + 1];
    u16x8 o;
    o[0] = f2b(a.x); o[1] = f2b(a.y); o[2] = f2b(a.z); o[3] = f2b(a.w);
    o[4] = f2b(b.x); o[5] = f2b(b.y); o[6] = f2b(b.z); o[7] = f2b(b.w);
    ((u16x8*)d)[(size_t)off] = o;
}

// ---------------------------------------------------------------------------
// NT GEMM, bf16 in / fp32 acc. 128x64 tile, BK=32, 4 waves, bijective XCD
// swizzle. QSCALE: cols<2048 scaled by 0.125*log2(e) (exp2-domain softmax).
// ---------------------------------------------------------------------------
template <bool OUT_BF16, bool QSCALE>
__global__ __launch_bounds__(256) void gemm_nt64(
    const u16* __restrict__ A, const u16* __restrict__ B,
    const float* __restrict__ bias, void* __restrict__ Cv,
    int N, int K, int nxb)
{
    __shared__ u16 As[128 * 32];
    __shared__ u16 Bs[64 * 32];
    const int nwg = gridDim.x;
    const int bid = blockIdx.x;
    const int wg  = (bid & 7) * (nwg >> 3) + (bid >> 3);
    const int bm  = (wg / nxb) * 128;
    const int bn  = (wg % nxb) * 64;

    const int tid  = threadIdx.x;
    const int lane = tid & 63;
    const int w    = tid >> 6;
    const int wr   = w >> 1, wc = w & 1;
    const int la = lane & 15, lg = lane >> 4;
    const int srow = lane >> 2;
    const int sseg = (lane & 3) * 8;

    f32x4 acc[4][2] = {};

    for (int k0 = 0; k0 < K; k0 += 32) {
        #pragma unroll
        for (int i = 0; i < 2; ++i) {
            const int c = w * 2 + i;
            gld16(A + (size_t)(bm + c * 16 + srow) * K + k0 + sseg, As + c * 512);
        }
        gld16(B + (size_t)(bn + w * 16 + srow) * K + k0 + sseg, Bs + w * 512);
        __syncthreads();
        bf16x8 af[4], bf[2];
        #pragma unroll
        for (int m = 0; m < 4; ++m)
            af[m] = *(const bf16x8*)(As + (wr * 64 + m * 16 + la) * 32 + lg * 8);
        #pragma unroll
        for (int n = 0; n < 2; ++n)
            bf[n] = *(const bf16x8*)(Bs + (wc * 32 + n * 16 + la) * 32 + lg * 8);
        #pragma unroll
        for (int m = 0; m < 4; ++m)
            #pragma unroll
            for (int n = 0; n < 2; ++n)
                acc[m][n] = MFMA16(af[m], bf[n], acc[m][n]);
        __syncthreads();
    }

    #pragma unroll
    for (int m = 0; m < 4; ++m) {
        #pragma unroll
        for (int n = 0; n < 2; ++n) {
            const int col = bn + wc * 32 + n * 16 + la;
            const float bb = bias[col];
            const float osc = (QSCALE && col < 2048) ? 0.180336881f : 1.0f;
            #pragma unroll
            for (int j = 0; j < 4; ++j) {
                const int row = bm + wr * 64 + m * 16 + lg * 4 + j;
                const float v = (acc[m][n][j] + bb) * osc;
                if (OUT_BF16) ((u16*)Cv)[(size_t)row * N + col] = f2b(v);
                else          ((float*)Cv)[(size_t)row * N + col] = v;
            }
        }
    }
}

// ---------------------------------------------------------------------------
__global__ __launch_bounds__(256) void kvrepack(const u16* __restrict__ QKVb,
                                                u16* __restrict__ Kp,
                                                u16* __restrict__ Vt) {
    const int h   = blockIdx.y;
    const int kt  = blockIdx.x;
    const int tid = threadIdx.x;
    __shared__ u16 T[64][72];
    #pragma unroll
    for (int p = 0; p < 2; ++p) {
        const int idx = p * 256 + tid;
        const int r   = idx >> 3;
        const int c8  = (idx & 7) * 8;
        *(u16x8*)&Kp[((size_t)h * S_LEN + kt * 64 + r) * 64 + c8] =
            *(const u16x8*)&QKVb[(size_t)(kt * 64 + r) * QKVW + 2048 + h * 64 + c8];
    }
    #pragma unroll
    for (int p = 0; p < 2; ++p) {
        const int r  = p * 32 + (tid >> 3);
        const int cs = (tid & 7) * 8;
        u16x8 v = *(const u16x8*)&QKVb[(size_t)(kt * 64 + r) * QKVW + 2560 + h * 64 + cs];
        #pragma unroll
        for (int j = 0; j < 8; ++j) T[r][cs + j] = v[j];
    }
    __syncthreads();
    #pragma unroll
    for (int p = 0; p < 2; ++p) {
        const int d  = p * 32 + (tid >> 3);
        const int ks = (tid & 7) * 8;
        u16x8 o;
        #pragma unroll
        for (int j = 0; j < 8; ++j) o[j] = T[ks + j][d];
        *(u16x8*)&Vt[((size_t)h * 64 + d) * S_LEN + kt * 64 + ks] = o;
    }
}

// ---------------------------------------------------------------------------
// Flash attention v6.1. Block = (32-row band, kv-head), 4 waves = 4 q-heads.
// Grid 512, all co-resident (2 blocks/CU); complementary band pairing
// balances per-CU work (~33 chunks). K/V chunks staged once per block into
// dbuf LDS (gld16, XOR-swizzled source). Swapped-QK^T 32x32 MFMA,
// exp2-domain in-register softmax, __shfl_xor cross-half exchanges (v5.1).
// ---------------------------------------------------------------------------
#define BUFB 8192   // bytes per K (or V) chunk buffer: 64 * 64 * 2

__global__ __launch_bounds__(256, 2) void attn(
    const u16* __restrict__ Qb,   // QKVb [2048][3072], Q cols pre-scaled
    const u16* __restrict__ Kp,   // [8][2048][64]
    const u16* __restrict__ Vt,   // [8][64][2048]
    u16* __restrict__ Ob)         // [2048][2048] bf16
{
    const int tid  = threadIdx.x;
    const int lane = tid & 63;
    const int w    = tid >> 6;           // 0..3 = q-head in group
    const int bid  = blockIdx.x;
    const int band = (bid < 256) ? (63 - (bid >> 3)) : ((bid - 256) >> 3);
    const int h    = bid & 7;
    const int hq   = h * 4 + w;
    const int q0   = band * 32;
    const int lq   = lane & 31;
    const int hi   = lane >> 5;

    __shared__ u16 Klds[2][64 * 64];
    __shared__ u16 Vlds[2][64 * 64];

    bf16x8 qf[4];
    #pragma unroll
    for (int ds = 0; ds < 4; ++ds)
        qf[ds] = *(const bf16x8*)&Qb[(size_t)(q0 + lq) * QKVW + hq * 64 + ds * 16 + hi * 8];

    f32x16 ot[2] = {};
    float m = -3e38f, lsum = 0.f;

    const char* Khb = (const char*)(Kp + (size_t)h * S_LEN * 64);   // 128 B/key
    const char* Vhb = (const char*)(Vt + (size_t)h * 64 * S_LEN);   // 4096 B/d-row

    // staging: thread stages rows r0 and r0+32 for K and V (4 x gld16).
    // LDS dest linear (wave-uniform base + lane*16); global source slot
    // pre-swizzled so LDS[row][slot] = global[row][slot ^ (row&7)].
    const int r0 = tid >> 3;
    const int s0 = (((tid & 7) ^ (r0 & 7)) << 4);
    char* const kuni = (char*)&Klds[0][0] + w * 1024;
    char* const vuni = (char*)&Vlds[0][0] + w * 1024;

    const int nch = (band >> 1) + 1;

    // prologue: stage chunk 0 into buf 0
    gld16(Khb + ((size_t)r0 << 7) + s0, kuni);
    gld16(Khb + ((size_t)(r0 + 32) << 7) + s0, kuni + 4096);
    gld16(Vhb + ((size_t)r0 << 12) + s0, vuni);
    gld16(Vhb + ((size_t)(r0 + 32) << 12) + s0, vuni + 4096);
    __syncthreads();

    int cur = 0;
    for (int c = 0; c < nch; ++c) {
        const int k0 = c * 64;

        // stage next chunk into the other buffer (overlaps with compute)
        if (c + 1 < nch) {
            const int nb = (cur ^ 1) * BUFB;
            const int kn = k0 + 64;
            gld16(Khb + ((size_t)(kn + r0) << 7) + s0, kuni + nb);
            gld16(Khb + ((size_t)(kn + r0 + 32) << 7) + s0, kuni + nb + 4096);
            gld16(Vhb + ((size_t)r0 << 12) + (kn << 1) + s0, vuni + nb);
            gld16(Vhb + ((size_t)(r0 + 32) << 12) + (kn << 1) + s0, vuni + nb + 4096);
        }

        const bool diag = (k0 + 63 > q0);
        const char* Kb = (const char*)&Klds[0][0] + cur * BUFB;
        const char* Vb = (const char*)&Vlds[0][0] + cur * BUFB;

        // ---- QK^T (swapped): S^T[key][q], exp2 domain
        f32x16 s[2];
        __builtin_amdgcn_s_setprio(1);
        #pragma unroll
        for (int kt = 0; kt < 2; ++kt) {
            f32x16 acc = {};
            #pragma unroll
            for (int ds = 0; ds < 4; ++ds) {
                const int key = kt * 32 + lq;
                const int byteK = (key << 7) + ((ds * 32 + hi * 16) ^ ((key & 7) << 4));
                bf16x8 kf = *(const bf16x8*)(Kb + byteK);
                acc = MFMA32(kf, qf[ds], acc);
            }
            s[kt] = acc;
        }
        __builtin_amdgcn_s_setprio(0);

        if (diag) {
            #pragma unroll
            for (int kt = 0; kt < 2; ++kt)
                #pragma unroll
                for (int r = 0; r < 16; ++r) {
                    const int key = k0 + kt * 32 + (r & 3) + 8 * (r >> 2) + 4 * hi;
                    if (key > q0 + lq) s[kt][r] = -1e30f;
                }
        }

        // ---- chunk max: pairwise tree + cross-half shfl
        float a16[16];
        #pragma unroll
        for (int r = 0; r < 16; ++r) a16[r] = fmaxf(s[0][r], s[1][r]);
        #pragma unroll
        for (int r = 0; r < 8; ++r) a16[r] = fmaxf(a16[r], a16[r + 8]);
        #pragma unroll
        for (int r = 0; r < 4; ++r) a16[r] = fmaxf(a16[r], a16[r + 4]);
        float pm = fmaxf(fmaxf(a16[0], a16[1]), fmaxf(a16[2], a16[3]));
        pm = fmaxf(pm, __shfl_xor(pm, 32));

        // ---- defer-max rescale (exp2 domain, THR = 8*log2e)
        if (!__all(pm <= m + 11.5f)) {
            const float mn   = fmaxf(m, pm);
            const float corr = __builtin_exp2f(m - mn);
            m = mn;
            lsum *= corr;
            #pragma unroll
            for (int r = 0; r < 16; ++r) {
                const int row = (r & 3) + 8 * (r >> 2) + 4 * hi;
                const float cr = __shfl(corr, row);
                ot[0][r] *= cr;
                ot[1][r] *= cr;
            }
        }

        // ---- P = exp2(S - m), row sums
        float ps = 0.f;
        #pragma unroll
        for (int kt = 0; kt < 2; ++kt)
            #pragma unroll
            for (int r = 0; r < 16; ++r) {
                const float p = __builtin_exp2f(s[kt][r] - m);
                s[kt][r] = p;
                ps += p;
            }
        lsum += ps + __shfl_xor(ps, 32);

        // ---- pack P -> 4 PV A-frags (v5.1 shfl_xor exchange)
        bf16x8 pa[4];
        #pragma unroll
        for (int kb = 0; kb < 4; ++kb) {
            const int kt = kb >> 1;
            const int rb = (kb & 1) * 8;
            const u32 A = pk2(s[kt][rb + 0], s[kt][rb + 1]);
            const u32 B = pk2(s[kt][rb + 4], s[kt][rb + 5]);
            const u32 C = pk2(s[kt][rb + 2], s[kt][rb + 3]);
            const u32 D = pk2(s[kt][rb + 6], s[kt][rb + 7]);
            const u32 sA = __shfl_xor(A, 32), sB = __shfl_xor(B, 32);
            const u32 sC = __shfl_xor(C, 32), sD = __shfl_xor(D, 32);
            u32x4 t4;
            t4[0] = hi ? sB : A;
            t4[1] = hi ? sD : C;
            t4[2] = hi ? B : sA;
            t4[3] = hi ? D : sC;
            pa[kb] = __builtin_bit_cast(bf16x8, t4);
        }

        // ---- PV: O += P @ V
        __builtin_amdgcn_s_setprio(1);
        #pragma unroll
        for (int dt = 0; dt < 2; ++dt)
            #pragma unroll
            for (int kb = 0; kb < 4; ++kb) {
                const int d = dt * 32 + lq;
                const int byteV = (d << 7) + ((kb * 32 + hi * 16) ^ ((d & 7) << 4));
                bf16x8 vf = *(const bf16x8*)(Vb + byteV);
                ot[dt] = MFMA32(pa[kb], vf, ot[dt]);
            }
        __builtin_amdgcn_s_setprio(0);

        // drain stage loads + handoff
        __syncthreads();
        cur ^= 1;
    }

    const float linv = 1.f / lsum;
    #pragma unroll
    for (int r = 0; r < 16; ++r) {
        const int row = (r & 3) + 8 * (r >> 2) + 4 * hi;
        const float lr = __shfl(linv, row);
        #pragma unroll
        for (int dt = 0; dt < 2; ++dt)
            Ob[(size_t)(q0 + row) * DM + hq * 64 + dt * 32 + lq] =
                f2b(ot[dt][r] * lr);
    }
}

// ---------------------------------------------------------------------------
extern "C" void kernel_launch(void* const* d_in, const int* in_sizes, int n_in,
                              void* d_out, int out_size, void* d_ws, size_t ws_size,
                              hipStream_t stream)
{
    const float* x  = (const float*)d_in[0];
    const float* wq = (const float*)d_in[1];
    const float* bq = (const float*)d_in[2];
    const float* wk = (const float*)d_in[3];
    const float* bk = (const float*)d_in[4];
    const float* wv = (const float*)d_in[5];
    const float* bv = (const float*)d_in[6];
    const float* wo = (const float*)d_in[7];
    const float* bo = (const float*)d_in[8];
    float* out = (float*)d_out;

    char* ws = (char*)d_ws;
    u16* xb     = (u16*)(ws);                  // 8 MB; dead after QKV GEMM
    u16* wqkvb  = (u16*)(ws + (8u  << 20));    // 12 MB; dead after QKV GEMM
    u16* wob    = (u16*)(ws + (20u << 20));    // 8 MB
    u16* QKVb   = (u16*)(ws + (28u << 20));    // 12 MB
    float* bqkv = (float*)(ws + (40u << 20));  // 12 KB
    u16* Ob = xb;                              // 8 MB (aliases dead xb)
    u16* Kp = wqkvb;                           // 2 MB (aliases dead wqkvb)
    u16* Vt = wqkvb + (size_t)2 * 1024 * 1024 / 2;  // 2 MB

    cvt5<<<7169, 256, 0, stream>>>(x, wq, wk, wv, wo, bq, bk, bv,
                                   xb, wqkvb, wob, bqkv);
    gemm_nt64<true, true><<<768, 256, 0, stream>>>(
        xb, wqkvb, bqkv, QKVb, QKVW, 2048, QKVW / 64);
    kvrepack<<<dim3(32, 8), 256, 0, stream>>>(QKVb, Kp, Vt);
    attn<<<512, 256, 0, stream>>>(QKVb, Kp, Vt, Ob);
    gemm_nt64<false, false><<<512, 256, 0, stream>>>(
        Ob, wob, bo, out, DM, 2048, DM / 64);
}